// Round 8
// baseline (128.840 us; speedup 1.0000x reference)
//
#include <hip/hip_runtime.h>
#include <hip/hip_bf16.h>
#include <math.h>

#define B_ 2
#define C_ 64
#define H_ 192
#define W_ 192
#define HW_ (H_*W_)
#define BHW_ (B_*HW_)
#define KK_ 9
#define CK_ (C_*KK_)      // 576
#define KSTEPS_ (CK_/32)  // 18

typedef __bf16 bf16x8 __attribute__((ext_vector_type(8)));
typedef float  f32x4  __attribute__((ext_vector_type(4)));
typedef unsigned short ushortx8 __attribute__((ext_vector_type(8)));
typedef unsigned short ushortx4 __attribute__((ext_vector_type(4)));

__device__ __forceinline__ float bf2f(unsigned short u) {
    unsigned int t = ((unsigned int)u) << 16;
    return __builtin_bit_cast(float, t);
}
__device__ __forceinline__ unsigned short f2bf(float f) {
    __hip_bfloat16 hb = __float2bfloat16(f);
    return *reinterpret_cast<unsigned short*>(&hb);
}

// ---------------- LayerNorm over channel axis -> bf16 NHWC ------------------
__global__ void ln_kernel(const float* __restrict__ x,
                          const float* __restrict__ lnw,
                          const float* __restrict__ lnb,
                          unsigned short* __restrict__ xnb) {   // [BHW][64]
    int p = blockIdx.x * blockDim.x + threadIdx.x;
    if (p >= BHW_) return;
    int b = p / HW_, pix = p % HW_;
    const float* xb = x + (size_t)b * C_ * HW_ + pix;
    float v[C_];
    float s = 0.f, s2 = 0.f;
    #pragma unroll
    for (int c = 0; c < C_; ++c) {
        v[c] = xb[(size_t)c * HW_];
        s += v[c]; s2 += v[c] * v[c];
    }
    float mu  = s * (1.0f / C_);
    float var = s2 * (1.0f / C_) - mu * mu;
    float inv = rsqrtf(var + 1e-5f);
    unsigned short* zb = xnb + (size_t)p * 64;
    #pragma unroll
    for (int g = 0; g < 8; ++g) {
        ushortx8 st;
        #pragma unroll
        for (int j = 0; j < 8; ++j) {
            int c = g * 8 + j;
            st[j] = f2bf((v[c] - mu) * inv * lnw[c] + lnb[c]);
        }
        *reinterpret_cast<ushortx8*>(zb + g * 8) = st;
    }
}

// ---------------- weight prepack (tap-outer ck = k*64+c) -------------------
__global__ void prepack_kernel(const float* __restrict__ dw,
                               const float* __restrict__ fw,
                               const float* __restrict__ offw,
                               const float* __restrict__ maskw,
                               unsigned short* __restrict__ wpack,
                               unsigned short* __restrict__ wpf,
                               unsigned short* __restrict__ wpc) {
    const int n1 = 4 * KSTEPS_ * 64 * 8;   // deform
    const int n2 = 4 * KSTEPS_ * 64 * 8;   // fusion
    const int n3 = 2 * KSTEPS_ * 64 * 8;   // conv27
    int gid = blockIdx.x * blockDim.x + threadIdx.x;
    int nth = gridDim.x * blockDim.x;
    for (int idx = gid; idx < n1 + n2 + n3; idx += nth) {
        int which = (idx < n1) ? 0 : (idx < n1 + n2 ? 1 : 2);
        int rem = idx - (which == 0 ? 0 : (which == 1 ? n1 : n1 + n2));
        int j = rem & 7;
        int l = (rem >> 3) & 63;
        int rest = rem >> 9;
        int s = rest % KSTEPS_;
        int t = rest / KSTEPS_;
        int oc = t * 16 + (l & 15);
        int ck = s * 32 + (l >> 4) * 8 + j;
        int k = ck >> 6, c = ck & 63;
        float v;
        if (which == 0) {
            v = dw[(size_t)oc * CK_ + c * 9 + k];
        } else if (which == 1) {
            v = fw[(size_t)oc * CK_ + c * 9 + k];
        } else {
            v = (oc < 18) ? offw[(size_t)oc * CK_ + c * 9 + k]
              : (oc < 27) ? maskw[(size_t)(oc - 18) * CK_ + c * 9 + k]
              : 0.f;
        }
        unsigned short u = f2bf(v);
        if (which == 0) wpack[rem] = u;
        else if (which == 1) wpf[rem] = u;
        else wpc[rem] = u;
    }
}

// ---------------- merged: conv27 + modulated deformable conv ---------------
// Phase 1: 27-ch offset/mask conv (MFMA), transpose via LDS so each lane
//          gets its own pixel's 27 values.
// Phase 2: tap-pipelined bilinear gather + 64-ch MFMA contraction.
__global__ void __launch_bounds__(256) dc_mfma(
        const unsigned short* __restrict__ xnb,   // NHWC
        const unsigned short* __restrict__ wpc,
        const float* __restrict__ offb, const float* __restrict__ maskb,
        const unsigned short* __restrict__ wpack,
        const float* __restrict__ db,
        unsigned short* __restrict__ xdefb) {     // NHWC
    __shared__ float som[4][16][36];   // pad 36: 2-way bank alias only
    int wave = threadIdx.x >> 6;
    int lane = threadIdx.x & 63;
    int ptile = blockIdx.x * 4 + wave;
    int pq = lane & 15;
    int p = ptile * 16 + pq;
    int kchunk = lane >> 4;
    int b = p / HW_, pix = p - b * HW_;
    int h = pix / W_, w = pix - h * W_;

    const unsigned short* xb = xnb + (size_t)b * HW_ * 64;

    // ---- phase 1: conv27, depth-2 load pipeline ----
    f32x4 cacc[2];
    cacc[0] = f32x4{0.f, 0.f, 0.f, 0.f};
    cacc[1] = f32x4{0.f, 0.f, 0.f, 0.f};

    auto ldconv = [&](int s) -> ushortx8 {
        const int k = s >> 1;
        const int dy = k / 3 - 1, dx = k % 3 - 1;
        bool ok = ((unsigned)(h + dy) < (unsigned)H_) &&
                  ((unsigned)(w + dx) < (unsigned)W_);
        int sp = ok ? (pix + dy * W_ + dx) : pix;
        int cbase = (s & 1) * 32 + kchunk * 8;
        return ok ? *reinterpret_cast<const ushortx8*>(xb + (size_t)sp * 64 + cbase)
                  : ushortx8{0, 0, 0, 0, 0, 0, 0, 0};
    };

    ushortx8 cb0 = ldconv(0);
    ushortx8 cb1 = ldconv(1);
    #pragma unroll
    for (int s = 0; s < KSTEPS_; ++s) {
        ushortx8 cur = (s & 1) ? cb1 : cb0;
        if (s + 2 < KSTEPS_) {
            if (s & 1) cb1 = ldconv(s + 2); else cb0 = ldconv(s + 2);
        }
        bf16x8 bv = __builtin_bit_cast(bf16x8, cur);
        #pragma unroll
        for (int t = 0; t < 2; ++t) {
            bf16x8 afrag = *reinterpret_cast<const bf16x8*>(
                wpc + ((size_t)(t * KSTEPS_ + s) * 64 + lane) * 8);
            cacc[t] = __builtin_amdgcn_mfma_f32_16x16x32_bf16(afrag, bv, cacc[t], 0, 0, 0);
        }
    }

    // bias / sigmoid, write to LDS transpose tile
    #pragma unroll
    for (int t = 0; t < 2; ++t) {
        f32x4 sv;
        #pragma unroll
        for (int r = 0; r < 4; ++r) {
            int oc = t * 16 + kchunk * 4 + r;
            float a = cacc[t][r];
            if (oc < 18)      sv[r] = a + offb[oc];
            else if (oc < 27) sv[r] = 1.f / (1.f + expf(-(a + maskb[oc - 18])));
            else              sv[r] = 0.f;
        }
        *reinterpret_cast<f32x4*>(&som[wave][pq][t * 16 + kchunk * 4]) = sv;
    }
    __syncthreads();

    float om[28];
    #pragma unroll
    for (int i = 0; i < 7; ++i) {
        f32x4 t4 = *reinterpret_cast<const f32x4*>(&som[wave][pq][4 * i]);
        om[4 * i + 0] = t4[0]; om[4 * i + 1] = t4[1];
        om[4 * i + 2] = t4[2]; om[4 * i + 3] = t4[3];
    }

    // ---- phase 2: gather + contraction, 1-tap-ahead pipeline ----
    f32x4 acc[4];
    #pragma unroll
    for (int t = 0; t < 4; ++t) acc[t] = f32x4{0.f, 0.f, 0.f, 0.f};

    ushortx8 g0[8], g1[8];      // two rolling slots (8 corner-loads each)
    float    q0[4], q1[4];

    auto issue = [&](int k, ushortx8* g, float* q) {
        float dy = om[2 * k], dx = om[2 * k + 1], m = om[18 + k];
        float py = dy + (float)(h - 1 + k / 3);
        float px = dx + (float)(w - 1 + k % 3);
        float fy = floorf(py), fx = floorf(px);
        float ly = py - fy, lx = px - fx;
        int y0 = (int)fy, x0 = (int)fx;
        int y1 = y0 + 1, x1 = x0 + 1;
        bool oky0 = (unsigned)y0 < (unsigned)H_;
        bool oky1 = (unsigned)y1 < (unsigned)H_;
        bool okx0 = (unsigned)x0 < (unsigned)W_;
        bool okx1 = (unsigned)x1 < (unsigned)W_;
        int cy0 = min(max(y0, 0), H_ - 1), cy1 = min(max(y1, 0), H_ - 1);
        int cx0 = min(max(x0, 0), W_ - 1), cx1 = min(max(x1, 0), W_ - 1);
        int a00 = cy0 * W_ + cx0, a01 = cy0 * W_ + cx1;
        int a10 = cy1 * W_ + cx0, a11 = cy1 * W_ + cx1;
        q[0] = (oky0 && okx0) ? (1.f - ly) * (1.f - lx) * m : 0.f;
        q[1] = (oky0 && okx1) ? (1.f - ly) * lx * m : 0.f;
        q[2] = (oky1 && okx0) ? ly * (1.f - lx) * m : 0.f;
        q[3] = (oky1 && okx1) ? ly * lx * m : 0.f;
        int cb = kchunk * 8;
        g[0] = *reinterpret_cast<const ushortx8*>(xb + (size_t)a00 * 64 + cb);
        g[1] = *reinterpret_cast<const ushortx8*>(xb + (size_t)a01 * 64 + cb);
        g[2] = *reinterpret_cast<const ushortx8*>(xb + (size_t)a10 * 64 + cb);
        g[3] = *reinterpret_cast<const ushortx8*>(xb + (size_t)a11 * 64 + cb);
        g[4] = *reinterpret_cast<const ushortx8*>(xb + (size_t)a00 * 64 + cb + 32);
        g[5] = *reinterpret_cast<const ushortx8*>(xb + (size_t)a01 * 64 + cb + 32);
        g[6] = *reinterpret_cast<const ushortx8*>(xb + (size_t)a10 * 64 + cb + 32);
        g[7] = *reinterpret_cast<const ushortx8*>(xb + (size_t)a11 * 64 + cb + 32);
    };

    issue(0, g0, q0);
    #pragma unroll
    for (int k = 0; k < KK_; ++k) {
        ushortx8* gc = (k & 1) ? g1 : g0;
        float*    qc = (k & 1) ? q1 : q0;
        if (k + 1 < KK_) {
            if (k & 1) issue(k + 1, g0, q0); else issue(k + 1, g1, q1);
        }
        #pragma unroll
        for (int half = 0; half < 2; ++half) {
            int s = k * 2 + half;
            union { unsigned short u[8]; bf16x8 v; } bu;
            #pragma unroll
            for (int j = 0; j < 8; ++j) {
                float v = qc[0] * bf2f(gc[half * 4 + 0][j])
                        + qc[1] * bf2f(gc[half * 4 + 1][j])
                        + qc[2] * bf2f(gc[half * 4 + 2][j])
                        + qc[3] * bf2f(gc[half * 4 + 3][j]);
                bu.u[j] = f2bf(v);
            }
            #pragma unroll
            for (int t = 0; t < 4; ++t) {
                bf16x8 afrag = *reinterpret_cast<const bf16x8*>(
                    wpack + ((size_t)(t * KSTEPS_ + s) * 64 + lane) * 8);
                acc[t] = __builtin_amdgcn_mfma_f32_16x16x32_bf16(afrag, bu.v, acc[t], 0, 0, 0);
            }
        }
    }

    unsigned short* zb = xdefb + (size_t)p * 64;
    #pragma unroll
    for (int t = 0; t < 4; ++t) {
        ushortx4 st;
        #pragma unroll
        for (int r = 0; r < 4; ++r) {
            int oc = t * 16 + kchunk * 4 + r;
            st[r] = f2bf(acc[t][r] + db[oc]);
        }
        *reinterpret_cast<ushortx4*>(zb + t * 16 + kchunk * 4) = st;
    }
}

// ---------------- fusion conv via MFMA + pre_mask blend --------------------
__global__ void __launch_bounds__(256) fuse_mfma(
        const unsigned short* __restrict__ xdefb,  // NHWC
        const unsigned short* __restrict__ wpf,
        const float* __restrict__ fb,
        const float* __restrict__ premask,
        const float* __restrict__ xin,             // NCHW
        float* __restrict__ out) {                 // NCHW
    int wave = threadIdx.x >> 6;
    int lane = threadIdx.x & 63;
    int ptile = blockIdx.x * 4 + wave;
    int p = ptile * 16 + (lane & 15);
    int kchunk = lane >> 4;
    int b = p / HW_, pix = p - b * HW_;
    int h = pix / W_, w = pix - h * W_;

    f32x4 acc[4];
    #pragma unroll
    for (int t = 0; t < 4; ++t) acc[t] = f32x4{0.f, 0.f, 0.f, 0.f};

    const unsigned short* xb = xdefb + (size_t)b * HW_ * 64;

    auto ldf = [&](int s) -> ushortx8 {
        const int k = s >> 1;
        const int dy = k / 3 - 1, dx = k % 3 - 1;
        bool ok = ((unsigned)(h + dy) < (unsigned)H_) &&
                  ((unsigned)(w + dx) < (unsigned)W_);
        int sp = ok ? (pix + dy * W_ + dx) : pix;
        int cbase = (s & 1) * 32 + kchunk * 8;
        return ok ? *reinterpret_cast<const ushortx8*>(xb + (size_t)sp * 64 + cbase)
                  : ushortx8{0, 0, 0, 0, 0, 0, 0, 0};
    };

    ushortx8 cb0 = ldf(0);
    ushortx8 cb1 = ldf(1);
    #pragma unroll
    for (int s = 0; s < KSTEPS_; ++s) {
        ushortx8 cur = (s & 1) ? cb1 : cb0;
        if (s + 2 < KSTEPS_) {
            if (s & 1) cb1 = ldf(s + 2); else cb0 = ldf(s + 2);
        }
        bf16x8 bv = __builtin_bit_cast(bf16x8, cur);
        #pragma unroll
        for (int t = 0; t < 4; ++t) {
            bf16x8 afrag = *reinterpret_cast<const bf16x8*>(
                wpf + ((size_t)(t * KSTEPS_ + s) * 64 + lane) * 8);
            acc[t] = __builtin_amdgcn_mfma_f32_16x16x32_bf16(afrag, bv, acc[t], 0, 0, 0);
        }
    }

    float pm = premask[(size_t)b * HW_ + pix];
    #pragma unroll
    for (int t = 0; t < 4; ++t) {
        #pragma unroll
        for (int r = 0; r < 4; ++r) {
            int oc = t * 16 + kchunk * 4 + r;
            size_t oidx = ((size_t)b * C_ + oc) * HW_ + pix;
            out[oidx] = (acc[t][r] + fb[oc]) * pm + xin[oidx] * (1.f - pm);
        }
    }
}

extern "C" void kernel_launch(void* const* d_in, const int* in_sizes, int n_in,
                              void* d_out, int out_size, void* d_ws, size_t ws_size,
                              hipStream_t stream) {
    const float* x       = (const float*)d_in[0];
    const float* premask = (const float*)d_in[1];
    const float* lnw     = (const float*)d_in[2];
    const float* lnb     = (const float*)d_in[3];
    const float* offw    = (const float*)d_in[4];
    const float* offb    = (const float*)d_in[5];
    const float* maskw   = (const float*)d_in[6];
    const float* maskb   = (const float*)d_in[7];
    const float* dw      = (const float*)d_in[8];
    const float* db      = (const float*)d_in[9];
    const float* fw      = (const float*)d_in[10];
    const float* fb      = (const float*)d_in[11];
    float* out = (float*)d_out;

    char* ws = (char*)d_ws;
    unsigned short* xnb   = (unsigned short*)ws;  ws += sizeof(short) * (size_t)BHW_ * 64;
    unsigned short* xdefb = (unsigned short*)ws;  ws += sizeof(short) * (size_t)BHW_ * 64;
    unsigned short* wpack = (unsigned short*)ws;  ws += sizeof(short) * 4 * KSTEPS_ * 64 * 8;
    unsigned short* wpf   = (unsigned short*)ws;  ws += sizeof(short) * 4 * KSTEPS_ * 64 * 8;
    unsigned short* wpc   = (unsigned short*)ws;  ws += sizeof(short) * 2 * KSTEPS_ * 64 * 8;

    ln_kernel<<<(BHW_ + 255) / 256, 256, 0, stream>>>(x, lnw, lnb, xnb);
    prepack_kernel<<<36, 256, 0, stream>>>(dw, fw, offw, maskw, wpack, wpf, wpc);
    dc_mfma<<<BHW_ / 64, 256, 0, stream>>>(
        xnb, wpc, offb, maskb, wpack, db, xdefb);
    fuse_mfma<<<BHW_ / 64, 256, 0, stream>>>(xdefb, wpf, fb, premask, x, out);
}